// Round 10
// baseline (323.122 us; speedup 1.0000x reference)
//
#include <hip/hip_runtime.h>
#include <math.h>

// Problem constants (SelfAttentionBlock): B=4, N=1500, E=256, H=8, DH=32, HID=512
#define B_    4
#define N_    1500
#define E_    256
#define H_    8
#define DH_   32
#define HID_  512
#define ROWS  (B_ * N_)          // 6000
#define EPS_  1e-6f
#define SCALE_ 0.17677669529663687f   // 1/sqrt(DH)
#define LOG2E_ 1.4426950408889634f
#define QSC_   (SCALE_ * LOG2E_)      // folded into stored Q
#define KMAIN  1472                   // 46 * 32; tail = keys 1472..1499

typedef _Float16 h4 __attribute__((ext_vector_type(4)));
typedef _Float16 h8 __attribute__((ext_vector_type(8)));
typedef float    f4 __attribute__((ext_vector_type(4)));

__device__ __forceinline__ int imin(int a, int b) { return a < b ? a : b; }

__device__ __forceinline__ float fast_exp2(float x) {
#if __has_builtin(__builtin_amdgcn_exp2f)
    return __builtin_amdgcn_exp2f(x);
#else
    return exp2f(x);
#endif
}
__device__ __forceinline__ float fast_sqrt(float x) {
#if __has_builtin(__builtin_amdgcn_sqrtf)
    return __builtin_amdgcn_sqrtf(x);
#else
    return sqrtf(x);
#endif
}

// ============================ LayerNorm (+beta, +packed coords) ============================
template<bool WITH_BETA>
__global__ __launch_bounds__(256)
void ln_kernel(const float* __restrict__ in, const float* __restrict__ w,
               const float* __restrict__ bvec, const float* __restrict__ beta_w,
               const float* __restrict__ beta_b, float* __restrict__ out,
               float* __restrict__ betaO, const float* __restrict__ points,
               float2* __restrict__ cpk)
{
    const int row = blockIdx.x;          // b*N + n
    const int t   = threadIdx.x;         // 0..255
    __shared__ float sm[4], sv[4];

    float v = in[(size_t)row * E_ + t];

    float s = v;
    #pragma unroll
    for (int o = 32; o; o >>= 1) s += __shfl_xor(s, o);
    if ((t & 63) == 0) sm[t >> 6] = s;
    __syncthreads();
    const float mu = (sm[0] + sm[1] + sm[2] + sm[3]) * (1.0f / E_);

    const float d = v - mu;
    float s2 = d * d;
    #pragma unroll
    for (int o = 32; o; o >>= 1) s2 += __shfl_xor(s2, o);
    if ((t & 63) == 0) sv[t >> 6] = s2;
    __syncthreads();
    const float var = (sv[0] + sv[1] + sv[2] + sv[3]) * (1.0f / E_);

    const float xv = d * rsqrtf(var + EPS_) * w[t] + bvec[t];
    out[(size_t)row * E_ + t] = xv;

    if (WITH_BETA) {
        if (t == 8) {   // pack xy coords once per row (aligned float2 table for attn)
            cpk[row] = make_float2(points[(size_t)row * 3 + 0], points[(size_t)row * 3 + 1]);
        }
        __shared__ float bs[H_][4];
        #pragma unroll
        for (int h = 0; h < H_; ++h) {
            float p = xv * beta_w[h * E_ + t];
            #pragma unroll
            for (int o = 32; o; o >>= 1) p += __shfl_xor(p, o);
            if ((t & 63) == 0) bs[h][t >> 6] = p;
        }
        __syncthreads();
        if (t < H_) {
            const int b = row / N_, n = row % N_;
            // fold log2e here: attention works natively in the exp2 domain
            betaO[((size_t)b * H_ + t) * N_ + n] =
                (bs[t][0] + bs[t][1] + bs[t][2] + bs[t][3] + beta_b[t]) * LOG2E_;
        }
    }
}

// ============================ Tiled fp32 GEMM ============================
enum { EPI_QKV = 0, EPI_BIAS_RES = 1, EPI_GELU = 2, EPI_BIAS = 3 };

template<int EPI>
__global__ __launch_bounds__(256)
void gemm_bt(const float* __restrict__ A, const float* __restrict__ Bw,
             const float* __restrict__ bias, const float* __restrict__ res,
             float* __restrict__ C, int M, int Nn, int K,
             _Float16* __restrict__ qh, _Float16* __restrict__ kh,
             _Float16* __restrict__ vt)
{
    __shared__ float As[16][68];
    __shared__ float Bs[16][68];

    const int m0 = blockIdx.x * 64, n0 = blockIdx.y * 64;
    const int tid = threadIdx.x;
    const int tx = tid & 15, ty = tid >> 4;
    const int lr = tid >> 2;
    const int lk = (tid & 3) << 2;

    const bool mval = (m0 + lr) < M;
    const bool nval = (n0 + lr) < Nn;
    const float* aptr = A  + (size_t)(m0 + lr) * K + lk;
    const float* bptr = Bw + (size_t)(n0 + lr) * K + lk;

    float acc[4][4] = {};

    for (int k0 = 0; k0 < K; k0 += 16) {
        float4 av = make_float4(0.f, 0.f, 0.f, 0.f);
        float4 bv = make_float4(0.f, 0.f, 0.f, 0.f);
        if (mval) av = *(const float4*)(aptr + k0);
        if (nval) bv = *(const float4*)(bptr + k0);
        As[lk + 0][lr] = av.x; As[lk + 1][lr] = av.y;
        As[lk + 2][lr] = av.z; As[lk + 3][lr] = av.w;
        Bs[lk + 0][lr] = bv.x; Bs[lk + 1][lr] = bv.y;
        Bs[lk + 2][lr] = bv.z; Bs[lk + 3][lr] = bv.w;
        __syncthreads();
        #pragma unroll
        for (int k = 0; k < 16; ++k) {
            float a[4], b[4];
            #pragma unroll
            for (int i = 0; i < 4; ++i) a[i] = As[k][ty * 4 + i];
            #pragma unroll
            for (int j = 0; j < 4; ++j) b[j] = Bs[k][tx * 4 + j];
            #pragma unroll
            for (int i = 0; i < 4; ++i)
                #pragma unroll
                for (int j = 0; j < 4; ++j)
                    acc[i][j] += a[i] * b[j];
        }
        __syncthreads();
    }

    // -------- epilogue --------
    if (EPI == EPI_QKV) {
        const int which = n0 >> 8;               // 0:q 1:k 2:v
        const int cb    = (n0 & 255) + tx * 4;   // 0..255, quad-aligned
        const int hh    = cb >> 5, dd = cb & 31;
        if (which < 2) {
            _Float16* base = (which == 0) ? qh : kh;
            const float scl = (which == 0) ? QSC_ : 1.0f;   // fold 1/sqrt(DH)*log2e into Q
            #pragma unroll
            for (int i = 0; i < 4; ++i) {
                const int mIdx = m0 + ty * 4 + i;
                if (mIdx >= M) continue;
                const int b = mIdx / N_, n = mIdx % N_;
                h4 pk;
                #pragma unroll
                for (int j = 0; j < 4; ++j)
                    pk[j] = (_Float16)((acc[i][j] + bias[n0 + tx * 4 + j]) * scl);
                *(h4*)(base + (((size_t)b * H_ + hh) * N_ + n) * DH_ + dd) = pk;
            }
        } else {
            // transposed store: vt[b,h,d,n]
            const int mq = m0 + ty * 4;
            if (mq < M) {
                const int b = mq / N_, n = mq % N_;
                #pragma unroll
                for (int j = 0; j < 4; ++j) {
                    h4 pv;
                    #pragma unroll
                    for (int i = 0; i < 4; ++i)
                        pv[i] = (_Float16)(acc[i][j] + bias[n0 + tx * 4 + j]);
                    *(h4*)(vt + (((size_t)b * H_ + hh) * DH_ + dd + j) * N_ + n) = pv;
                }
            }
        }
        return;
    }

    #pragma unroll
    for (int i = 0; i < 4; ++i) {
        const int mIdx = m0 + ty * 4 + i;
        if (mIdx >= M) continue;
        #pragma unroll
        for (int j = 0; j < 4; ++j) {
            const int nIdx = n0 + tx * 4 + j;
            if (nIdx >= Nn) continue;
            float vv = acc[i][j] + bias[nIdx];
            if (EPI == EPI_BIAS_RES) {
                C[(size_t)mIdx * Nn + nIdx] = vv + res[(size_t)mIdx * Nn + nIdx];
            } else if (EPI == EPI_GELU) {
                C[(size_t)mIdx * Nn + nIdx] =
                    vv * 0.5f * (1.0f + erff(vv * 0.70710678118654752f));
            } else { // EPI_BIAS
                C[(size_t)mIdx * Nn + nIdx] = vv;
            }
        }
    }
}

// ============================ MFMA flash attention (prefetched 32-k iterations) ============
// grid = (ceil(N/64), B*H), 256 threads = 4 waves; each wave owns 16 q rows.
// Swapped QK^T: S' = mfma_16x16x32_f16(Kfrag, Qfrag): lane holds s[q=lane&15][k=4g+j].
// S' frag IS the PV A-frag. Scores are natively log2-domain (scales folded upstream).
// r7 counters: 3.9K cyc/iter vs ~300-cyc compute chain => in-loop loads serialize.
// Fix: register double-buffer — iteration i issues i+1's 7 loads before computing,
// so the s_waitcnt lands one full iteration later. Final-iteration over-prefetch
// reads <=240B past kh into adjacent ws regions (in-bounds, discarded).
__global__ __launch_bounds__(256)
void attn_mfma(const _Float16* __restrict__ qh, const _Float16* __restrict__ kh,
               const _Float16* __restrict__ vt, const float2* __restrict__ cpk,
               const float* __restrict__ betaB, float* __restrict__ attnO)
{
    const int bh = blockIdx.y;
    const int b  = bh >> 3, h = bh & 7;
    const int wid  = threadIdx.x >> 6;
    const int lane = threadIdx.x & 63;
    const int qc = lane & 15;            // q col in S' / d col in O
    const int g  = lane >> 4;            // 16-lane group
    const int q0 = blockIdx.x * 64 + wid * 16;
    const int qcl = imin(q0 + qc, N_ - 1);

    const h8 qf = *(const h8*)(qh + ((size_t)bh * N_ + qcl) * DH_ + 8 * g);
    const float2 cq  = cpk[b * N_ + qcl];
    const float  nb2 = -betaB[(size_t)bh * N_ + qcl];   // -(beta*log2e)

    const _Float16* krow  = kh + (size_t)bh * N_ * DH_;
    const _Float16* vrow0 = vt + ((size_t)bh * DH_ + qc) * N_;
    const _Float16* vrow1 = vt + ((size_t)bh * DH_ + 16 + qc) * N_;
    const float2*   cpb   = cpk + b * N_;

    // hot-loop pointers (per-lane, incremented; offsets become immediates)
    const _Float16* kp  = krow + (size_t)qc * DH_ + 8 * g;
    const _Float16* v0p = vrow0 + 4 * g;
    const _Float16* v1p = vrow1 + 4 * g;
    const float4*   cp4 = (const float4*)(cpb + 4 * g);   // 4g even -> float4-aligned

    float m = -INFINITY, l = 0.0f, l2 = 0.0f;
    f4 acc0 = {0.f, 0.f, 0.f, 0.f}, acc1 = {0.f, 0.f, 0.f, 0.f};

    // ---- prefetch iteration 0 ----
    h8 kf0 = *(const h8*)(kp);
    h8 kf1 = *(const h8*)(kp + 16 * DH_);
    h4 va0 = *(const h4*)(v0p);
    h4 va1 = *(const h4*)(v0p + 16);
    h4 vb0 = *(const h4*)(v1p);
    h4 vb1 = *(const h4*)(v1p + 16);
    float4 c01a = cp4[0], c23a = cp4[1];
    float4 c01b = cp4[8], c23b = cp4[9];

    for (int kb = 0; kb < KMAIN; kb += 32) {
        // ---- issue next iteration's loads (fly under this iteration's compute) ----
        kp += 32 * DH_; v0p += 32; v1p += 32; cp4 += 16;
        const h8 kf0n = *(const h8*)(kp);
        const h8 kf1n = *(const h8*)(kp + 16 * DH_);
        const h4 va0n = *(const h4*)(v0p);
        const h4 va1n = *(const h4*)(v0p + 16);
        const h4 vb0n = *(const h4*)(v1p);
        const h4 vb1n = *(const h4*)(v1p + 16);
        const float4 c01an = cp4[0], c23an = cp4[1];
        const float4 c01bn = cp4[8], c23bn = cp4[9];

        // ---- compute on current registers ----
        const f4 s0 = __builtin_amdgcn_mfma_f32_16x16x32_f16(kf0, qf, (f4){0.f,0.f,0.f,0.f}, 0, 0, 0);
        const f4 s1 = __builtin_amdgcn_mfma_f32_16x16x32_f16(kf1, qf, (f4){0.f,0.f,0.f,0.f}, 0, 0, 0);

        const float cxa[4] = {c01a.x, c01a.z, c23a.x, c23a.z};
        const float cya[4] = {c01a.y, c01a.w, c23a.y, c23a.w};
        const float cxb[4] = {c01b.x, c01b.z, c23b.x, c23b.z};
        const float cyb[4] = {c01b.y, c01b.w, c23b.y, c23b.w};

        float sv0[4], sv1[4];
        float pmax = -INFINITY;
        #pragma unroll
        for (int j = 0; j < 4; ++j) {
            const float dx = cq.x - cxa[j], dy = cq.y - cya[j];
            const float r  = fast_sqrt(fmaf(dx, dx, dy * dy));
            sv0[j] = fmaf(r, nb2, s0[j]);
            pmax = fmaxf(pmax, sv0[j]);
        }
        #pragma unroll
        for (int j = 0; j < 4; ++j) {
            const float dx = cq.x - cxb[j], dy = cq.y - cyb[j];
            const float r  = fast_sqrt(fmaf(dx, dx, dy * dy));
            sv1[j] = fmaf(r, nb2, s1[j]);
            pmax = fmaxf(pmax, sv1[j]);
        }
        pmax = fmaxf(pmax, __shfl_xor(pmax, 16));
        pmax = fmaxf(pmax, __shfl_xor(pmax, 32));

        if (__any(pmax > m)) {
            const float mn = fmaxf(m, pmax);
            const float f  = fast_exp2(m - mn);
            m = mn; l *= f; l2 *= f;
            #pragma unroll
            for (int j = 0; j < 4; ++j) {
                const float fj = __shfl(f, 4 * g + j);
                acc0[j] *= fj; acc1[j] *= fj;
            }
        }

        h4 pa0, pa1;
        #pragma unroll
        for (int j = 0; j < 4; ++j) {
            const float p = fast_exp2(sv0[j] - m);
            l += p; pa0[j] = (_Float16)p;
        }
        #pragma unroll
        for (int j = 0; j < 4; ++j) {
            const float p = fast_exp2(sv1[j] - m);
            l2 += p; pa1[j] = (_Float16)p;
        }
        acc0 = __builtin_amdgcn_mfma_f32_16x16x16f16(pa0, va0, acc0, 0, 0, 0);
        acc0 = __builtin_amdgcn_mfma_f32_16x16x16f16(pa1, va1, acc0, 0, 0, 0);
        acc1 = __builtin_amdgcn_mfma_f32_16x16x16f16(pa0, vb0, acc1, 0, 0, 0);
        acc1 = __builtin_amdgcn_mfma_f32_16x16x16f16(pa1, vb1, acc1, 0, 0, 0);

        // ---- rotate ----
        kf0 = kf0n; kf1 = kf1n;
        va0 = va0n; va1 = va1n; vb0 = vb0n; vb1 = vb1n;
        c01a = c01an; c23a = c23an; c01b = c01bn; c23b = c23bn;
    }

    // ---- tail: keys 1472..1499 (first 16 full, second group masked >=1500) ----
    {
        const int kb = KMAIN;
        const h8 kf0t = *(const h8*)(krow + (size_t)(kb + qc) * DH_ + 8 * g);
        const h8 kf1t = *(const h8*)(krow + (size_t)imin(kb + 16 + qc, N_ - 1) * DH_ + 8 * g);
        const h4 va0t = *(const h4*)(vrow0 + kb + 4 * g);
        const h4 vb0t = *(const h4*)(vrow1 + kb + 4 * g);
        const int t1 = imin(kb + 16 + 4 * g, N_ - 4);
        const h4 va1t = *(const h4*)(vrow0 + t1);
        const h4 vb1t = *(const h4*)(vrow1 + t1);

        const f4 s0 = __builtin_amdgcn_mfma_f32_16x16x32_f16(kf0t, qf, (f4){0.f,0.f,0.f,0.f}, 0, 0, 0);
        const f4 s1 = __builtin_amdgcn_mfma_f32_16x16x32_f16(kf1t, qf, (f4){0.f,0.f,0.f,0.f}, 0, 0, 0);

        float sv0[4], sv1[4];
        float pmax = -INFINITY;
        #pragma unroll
        for (int j = 0; j < 4; ++j) {
            const int k = kb + 4 * g + j;                    // <= 1487, valid
            const float2 ck = cpb[k];
            const float dx = cq.x - ck.x, dy = cq.y - ck.y;
            const float r  = fast_sqrt(fmaf(dx, dx, dy * dy));
            sv0[j] = fmaf(r, nb2, s0[j]);
            pmax = fmaxf(pmax, sv0[j]);
        }
        #pragma unroll
        for (int j = 0; j < 4; ++j) {
            const int k = kb + 16 + 4 * g + j;
            const float2 ck = cpb[imin(k, N_ - 1)];
            const float dx = cq.x - ck.x, dy = cq.y - ck.y;
            const float r  = fast_sqrt(fmaf(dx, dx, dy * dy));
            const float sc = fmaf(r, nb2, s1[j]);
            sv1[j] = (k < N_) ? sc : -1.0e30f;
            pmax = fmaxf(pmax, sv1[j]);
        }
        pmax = fmaxf(pmax, __shfl_xor(pmax, 16));
        pmax = fmaxf(pmax, __shfl_xor(pmax, 32));

        if (__any(pmax > m)) {
            const float mn = fmaxf(m, pmax);
            const float f  = fast_exp2(m - mn);
            m = mn; l *= f; l2 *= f;
            #pragma unroll
            for (int j = 0; j < 4; ++j) {
                const float fj = __shfl(f, 4 * g + j);
                acc0[j] *= fj; acc1[j] *= fj;
            }
        }

        h4 pa0, pa1;
        #pragma unroll
        for (int j = 0; j < 4; ++j) {
            const float p = fast_exp2(sv0[j] - m);
            l += p; pa0[j] = (_Float16)p;
        }
        #pragma unroll
        for (int j = 0; j < 4; ++j) {
            const float p = fast_exp2(sv1[j] - m);
            l2 += p; pa1[j] = (_Float16)p;
        }
        acc0 = __builtin_amdgcn_mfma_f32_16x16x16f16(pa0, va0t, acc0, 0, 0, 0);
        acc0 = __builtin_amdgcn_mfma_f32_16x16x16f16(pa1, va1t, acc0, 0, 0, 0);
        acc1 = __builtin_amdgcn_mfma_f32_16x16x16f16(pa0, vb0t, acc1, 0, 0, 0);
        acc1 = __builtin_amdgcn_mfma_f32_16x16x16f16(pa1, vb1t, acc1, 0, 0, 0);
    }

    l += l2;
    l += __shfl_xor(l, 16);
    l += __shfl_xor(l, 32);

    #pragma unroll
    for (int j = 0; j < 4; ++j) {
        const int qo = q0 + 4 * g + j;
        const float lj = __shfl(l, 4 * g + j);
        if (qo < N_) {
            const float inv = 1.0f / lj;
            float* dst = attnO + ((size_t)b * N_ + qo) * E_ + h * DH_;
            dst[qc]      = acc0[j] * inv;
            dst[16 + qc] = acc1[j] * inv;
        }
    }
}

// ============================ launcher ============================
extern "C" void kernel_launch(void* const* d_in, const int* in_sizes, int n_in,
                              void* d_out, int out_size, void* d_ws, size_t ws_size,
                              hipStream_t stream)
{
    (void)in_sizes; (void)n_in; (void)out_size; (void)ws_size;
    const float* feat   = (const float*)d_in[0];
    const float* points = (const float*)d_in[1];
    const float* ln1_w  = (const float*)d_in[2];
    const float* ln1_b  = (const float*)d_in[3];
    const float* beta_w = (const float*)d_in[4];
    const float* beta_b = (const float*)d_in[5];
    const float* in_w   = (const float*)d_in[6];
    const float* in_b   = (const float*)d_in[7];
    const float* out_w  = (const float*)d_in[8];
    const float* out_b  = (const float*)d_in[9];
    const float* ln2_w  = (const float*)d_in[10];
    const float* ln2_b  = (const float*)d_in[11];
    const float* fc1_w  = (const float*)d_in[12];
    const float* fc1_b  = (const float*)d_in[13];
    const float* fc2_w  = (const float*)d_in[14];
    const float* fc2_b  = (const float*)d_in[15];
    float* out = (float*)d_out;

    // workspace layout (float offsets); peak 6,984,000 floats = 27.9 MB
    float* ws   = (float*)d_ws;
    float*     x    = ws;                               // 1,536,000 f32
    float*     beta = x + 1536000;                      //    48,000 f32
    float2*    cpk  = (float2*)(beta + 48000);          //     6,000 float2
    _Float16*  qh   = (_Float16*)(beta + 48000 + 24000);// 1,536,000 f16
    _Float16*  kh   = qh + 1536000;
    _Float16*  vt   = kh + 1536000;
    float*     attn = (float*)(vt + 1536000);           // 1,536,000 f32
    float*     f2   = attn + 1536000;                   // 1,536,000 f32
    float*     y2   = x;                                // reuse (x dead after QKV)
    float*     h1   = (float*)qh;                       // reuse 3,072,000 f32

    ln_kernel<true><<<ROWS, 256, 0, stream>>>(feat, ln1_w, ln1_b, beta_w, beta_b,
                                              x, beta, points, cpk);

    dim3 gqkv((ROWS + 63) / 64, (3 * E_ + 63) / 64);
    gemm_bt<EPI_QKV><<<gqkv, 256, 0, stream>>>(x, in_w, in_b, nullptr, nullptr,
                                               ROWS, 3 * E_, E_, qh, kh, vt);

    dim3 gatt((N_ + 63) / 64, B_ * H_);
    attn_mfma<<<gatt, 256, 0, stream>>>(qh, kh, vt, cpk, beta, attn);

    dim3 gout((ROWS + 63) / 64, (E_ + 63) / 64);
    gemm_bt<EPI_BIAS_RES><<<gout, 256, 0, stream>>>(attn, out_w, out_b, feat, f2,
                                                    ROWS, E_, E_, nullptr, nullptr, nullptr);

    ln_kernel<false><<<ROWS, 256, 0, stream>>>(f2, ln2_w, ln2_b, nullptr, nullptr,
                                               y2, nullptr, nullptr, nullptr);

    dim3 gfc1((ROWS + 63) / 64, (HID_ + 63) / 64);
    gemm_bt<EPI_GELU><<<gfc1, 256, 0, stream>>>(y2, fc1_w, fc1_b, nullptr, h1,
                                                ROWS, HID_, E_, nullptr, nullptr, nullptr);

    dim3 gfc2((ROWS + 63) / 64, (E_ + 63) / 64);
    gemm_bt<EPI_BIAS><<<gfc2, 256, 0, stream>>>(h1, fc2_w, fc2_b, nullptr, out,
                                                ROWS, E_, HID_, nullptr, nullptr, nullptr);
}

// Round 11
// 295.049 us; speedup vs baseline: 1.0951x; 1.0951x over previous
//
#include <hip/hip_runtime.h>
#include <math.h>

// Problem constants (SelfAttentionBlock): B=4, N=1500, E=256, H=8, DH=32, HID=512
#define B_    4
#define N_    1500
#define E_    256
#define H_    8
#define DH_   32
#define HID_  512
#define ROWS  (B_ * N_)          // 6000
#define EPS_  1e-6f
#define SCALE_ 0.17677669529663687f   // 1/sqrt(DH)
#define LOG2E_ 1.4426950408889634f
#define QSC_   (SCALE_ * LOG2E_)      // folded into stored Q
#define KMAIN  1472                   // 23 * 64; tail = keys 1472..1499

typedef _Float16 h4 __attribute__((ext_vector_type(4)));
typedef _Float16 h8 __attribute__((ext_vector_type(8)));
typedef float    f4 __attribute__((ext_vector_type(4)));

__device__ __forceinline__ int imin(int a, int b) { return a < b ? a : b; }

__device__ __forceinline__ float fast_exp2(float x) {
#if __has_builtin(__builtin_amdgcn_exp2f)
    return __builtin_amdgcn_exp2f(x);
#else
    return exp2f(x);
#endif
}
__device__ __forceinline__ float fast_sqrt(float x) {
#if __has_builtin(__builtin_amdgcn_sqrtf)
    return __builtin_amdgcn_sqrtf(x);
#else
    return sqrtf(x);
#endif
}

// ============================ LayerNorm (+beta, +packed coords) ============================
template<bool WITH_BETA>
__global__ __launch_bounds__(256)
void ln_kernel(const float* __restrict__ in, const float* __restrict__ w,
               const float* __restrict__ bvec, const float* __restrict__ beta_w,
               const float* __restrict__ beta_b, float* __restrict__ out,
               float* __restrict__ betaO, const float* __restrict__ points,
               float2* __restrict__ cpk)
{
    const int row = blockIdx.x;          // b*N + n
    const int t   = threadIdx.x;         // 0..255
    __shared__ float sm[4], sv[4];

    float v = in[(size_t)row * E_ + t];

    float s = v;
    #pragma unroll
    for (int o = 32; o; o >>= 1) s += __shfl_xor(s, o);
    if ((t & 63) == 0) sm[t >> 6] = s;
    __syncthreads();
    const float mu = (sm[0] + sm[1] + sm[2] + sm[3]) * (1.0f / E_);

    const float d = v - mu;
    float s2 = d * d;
    #pragma unroll
    for (int o = 32; o; o >>= 1) s2 += __shfl_xor(s2, o);
    if ((t & 63) == 0) sv[t >> 6] = s2;
    __syncthreads();
    const float var = (sv[0] + sv[1] + sv[2] + sv[3]) * (1.0f / E_);

    const float xv = d * rsqrtf(var + EPS_) * w[t] + bvec[t];
    out[(size_t)row * E_ + t] = xv;

    if (WITH_BETA) {
        if (t == 8) {   // pack xy coords once per row (aligned float2 table for attn)
            cpk[row] = make_float2(points[(size_t)row * 3 + 0], points[(size_t)row * 3 + 1]);
        }
        __shared__ float bs[H_][4];
        #pragma unroll
        for (int h = 0; h < H_; ++h) {
            float p = xv * beta_w[h * E_ + t];
            #pragma unroll
            for (int o = 32; o; o >>= 1) p += __shfl_xor(p, o);
            if ((t & 63) == 0) bs[h][t >> 6] = p;
        }
        __syncthreads();
        if (t < H_) {
            const int b = row / N_, n = row % N_;
            // fold log2e here: attention works natively in the exp2 domain
            betaO[((size_t)b * H_ + t) * N_ + n] =
                (bs[t][0] + bs[t][1] + bs[t][2] + bs[t][3] + beta_b[t]) * LOG2E_;
        }
    }
}

// ============================ Tiled fp32 GEMM ============================
enum { EPI_QKV = 0, EPI_BIAS_RES = 1, EPI_GELU = 2, EPI_BIAS = 3 };

template<int EPI>
__global__ __launch_bounds__(256)
void gemm_bt(const float* __restrict__ A, const float* __restrict__ Bw,
             const float* __restrict__ bias, const float* __restrict__ res,
             float* __restrict__ C, int M, int Nn, int K,
             _Float16* __restrict__ qh, _Float16* __restrict__ kh,
             _Float16* __restrict__ vt)
{
    __shared__ float As[16][68];
    __shared__ float Bs[16][68];

    const int m0 = blockIdx.x * 64, n0 = blockIdx.y * 64;
    const int tid = threadIdx.x;
    const int tx = tid & 15, ty = tid >> 4;
    const int lr = tid >> 2;
    const int lk = (tid & 3) << 2;

    const bool mval = (m0 + lr) < M;
    const bool nval = (n0 + lr) < Nn;
    const float* aptr = A  + (size_t)(m0 + lr) * K + lk;
    const float* bptr = Bw + (size_t)(n0 + lr) * K + lk;

    float acc[4][4] = {};

    for (int k0 = 0; k0 < K; k0 += 16) {
        float4 av = make_float4(0.f, 0.f, 0.f, 0.f);
        float4 bv = make_float4(0.f, 0.f, 0.f, 0.f);
        if (mval) av = *(const float4*)(aptr + k0);
        if (nval) bv = *(const float4*)(bptr + k0);
        As[lk + 0][lr] = av.x; As[lk + 1][lr] = av.y;
        As[lk + 2][lr] = av.z; As[lk + 3][lr] = av.w;
        Bs[lk + 0][lr] = bv.x; Bs[lk + 1][lr] = bv.y;
        Bs[lk + 2][lr] = bv.z; Bs[lk + 3][lr] = bv.w;
        __syncthreads();
        #pragma unroll
        for (int k = 0; k < 16; ++k) {
            float a[4], b[4];
            #pragma unroll
            for (int i = 0; i < 4; ++i) a[i] = As[k][ty * 4 + i];
            #pragma unroll
            for (int j = 0; j < 4; ++j) b[j] = Bs[k][tx * 4 + j];
            #pragma unroll
            for (int i = 0; i < 4; ++i)
                #pragma unroll
                for (int j = 0; j < 4; ++j)
                    acc[i][j] += a[i] * b[j];
        }
        __syncthreads();
    }

    // -------- epilogue --------
    if (EPI == EPI_QKV) {
        const int which = n0 >> 8;               // 0:q 1:k 2:v
        const int cb    = (n0 & 255) + tx * 4;   // 0..255, quad-aligned
        const int hh    = cb >> 5, dd = cb & 31;
        if (which < 2) {
            _Float16* base = (which == 0) ? qh : kh;
            const float scl = (which == 0) ? QSC_ : 1.0f;   // fold 1/sqrt(DH)*log2e into Q
            #pragma unroll
            for (int i = 0; i < 4; ++i) {
                const int mIdx = m0 + ty * 4 + i;
                if (mIdx >= M) continue;
                const int b = mIdx / N_, n = mIdx % N_;
                h4 pk;
                #pragma unroll
                for (int j = 0; j < 4; ++j)
                    pk[j] = (_Float16)((acc[i][j] + bias[n0 + tx * 4 + j]) * scl);
                *(h4*)(base + (((size_t)b * H_ + hh) * N_ + n) * DH_ + dd) = pk;
            }
        } else {
            // transposed store: vt[b,h,d,n]
            const int mq = m0 + ty * 4;
            if (mq < M) {
                const int b = mq / N_, n = mq % N_;
                #pragma unroll
                for (int j = 0; j < 4; ++j) {
                    h4 pv;
                    #pragma unroll
                    for (int i = 0; i < 4; ++i)
                        pv[i] = (_Float16)(acc[i][j] + bias[n0 + tx * 4 + j]);
                    *(h4*)(vt + (((size_t)b * H_ + hh) * DH_ + dd + j) * N_ + n) = pv;
                }
            }
        }
        return;
    }

    #pragma unroll
    for (int i = 0; i < 4; ++i) {
        const int mIdx = m0 + ty * 4 + i;
        if (mIdx >= M) continue;
        #pragma unroll
        for (int j = 0; j < 4; ++j) {
            const int nIdx = n0 + tx * 4 + j;
            if (nIdx >= Nn) continue;
            float vv = acc[i][j] + bias[nIdx];
            if (EPI == EPI_BIAS_RES) {
                C[(size_t)mIdx * Nn + nIdx] = vv + res[(size_t)mIdx * Nn + nIdx];
            } else if (EPI == EPI_GELU) {
                C[(size_t)mIdx * Nn + nIdx] =
                    vv * 0.5f * (1.0f + erff(vv * 0.70710678118654752f));
            } else { // EPI_BIAS
                C[(size_t)mIdx * Nn + nIdx] = vv;
            }
        }
    }
}

// ============================ MFMA flash attention (LDS V + XCD swizzle) ============
// r10 post-mortem: prefetch neutral -> bottleneck is V gather TXN ISSUE, not latency:
// each 8B V load touches 16 lines (qc x 3000B stride), x4 loads x4 waves per block
// on one L1 = ~256 txns per 32 keys. Plus L2 thrash (6.1MB/XCD > 4MB).
// Fix 1: stage V^T tile (32d x 64k) in LDS once per BLOCK (coalesced 8B copies,
//        rows padded to 144B -> 2-way-conflict ds_read_b64 fragments = free).
// Fix 2: XCD swizzle — all 24 q-tiles of a head on one XCD (768KB/XCD working set).
// Numerics identical to r7/r10 (same values, same order) -> absmax must reproduce.
__global__ __launch_bounds__(256)
void attn_mfma(const _Float16* __restrict__ qh, const _Float16* __restrict__ kh,
               const _Float16* __restrict__ vt, const float2* __restrict__ cpk,
               const float* __restrict__ betaB, float* __restrict__ attnO)
{
    // bijective swizzle (768 = 96 x 8): dispatch i -> XCD i%8 (round-robin heuristic)
    const int i    = blockIdx.x;            // 0..767
    const int slot = i >> 3;                // 0..95
    const int bh   = (i & 7) + 8 * (slot / 24);   // head on XCD bh%8
    const int qblk = slot % 24;

    const int b  = bh >> 3, h = bh & 7;
    const int tid  = threadIdx.x;
    const int wid  = tid >> 6;
    const int lane = tid & 63;
    const int qc = lane & 15;            // q col in S' / d col in O
    const int g  = lane >> 4;            // 16-lane group
    const int q0 = qblk * 64 + wid * 16;
    const int qcl = imin(q0 + qc, N_ - 1);

    __shared__ _Float16 Vs[32][72];      // V^T tile [d][key64], rows padded to 144B

    const h8 qf = *(const h8*)(qh + ((size_t)bh * N_ + qcl) * DH_ + 8 * g);
    const float2 cq  = cpk[b * N_ + qcl];
    const float  nb2 = -betaB[(size_t)bh * N_ + qcl];   // -(beta*log2e)

    const _Float16* krow  = kh + (size_t)bh * N_ * DH_;
    const _Float16* vtb   = vt + (size_t)bh * DH_ * N_;
    const _Float16* vrow0 = vtb + (size_t)qc * N_;        // tail path
    const _Float16* vrow1 = vtb + (size_t)(16 + qc) * N_; // tail path
    const float2*   cpb   = cpk + b * N_;

    // staging: 512 x 8B chunks, 2 per thread (vt rows are 8B-aligned, not 16B)
    const int r0 = tid >> 4;             // 0..15
    const int r1 = r0 + 16;              // 16..31
    const int c0 = (tid & 15) * 4;       // 0..60 (h16 units)

    float m = -INFINITY, l = 0.0f, l2 = 0.0f;
    f4 acc0 = {0.f, 0.f, 0.f, 0.f}, acc1 = {0.f, 0.f, 0.f, 0.f};

    for (int tkb = 0; tkb < KMAIN; tkb += 64) {
        __syncthreads();   // previous tile's Vs reads complete before overwrite
        *(h4*)&Vs[r0][c0] = *(const h4*)(vtb + (size_t)r0 * N_ + tkb + c0);
        *(h4*)&Vs[r1][c0] = *(const h4*)(vtb + (size_t)r1 * N_ + tkb + c0);
        __syncthreads();   // staging visible to all waves

        #pragma unroll
        for (int s = 0; s < 2; ++s) {
            const int kb = tkb + 32 * s;
            const h8 kf0 = *(const h8*)(krow + (size_t)(kb + qc) * DH_ + 8 * g);
            const h8 kf1 = *(const h8*)(krow + (size_t)(kb + 16 + qc) * DH_ + 8 * g);
            const h4 va0 = *(const h4*)&Vs[qc][32 * s + 4 * g];
            const h4 va1 = *(const h4*)&Vs[qc][32 * s + 16 + 4 * g];
            const h4 vb0 = *(const h4*)&Vs[16 + qc][32 * s + 4 * g];
            const h4 vb1 = *(const h4*)&Vs[16 + qc][32 * s + 16 + 4 * g];
            const float4* cpt = (const float4*)(cpb + kb);   // kb even -> 16B aligned
            const float4 c01a = cpt[2 * g],     c23a = cpt[2 * g + 1];
            const float4 c01b = cpt[8 + 2 * g], c23b = cpt[8 + 2 * g + 1];

            const f4 s0 = __builtin_amdgcn_mfma_f32_16x16x32_f16(kf0, qf, (f4){0.f,0.f,0.f,0.f}, 0, 0, 0);
            const f4 s1 = __builtin_amdgcn_mfma_f32_16x16x32_f16(kf1, qf, (f4){0.f,0.f,0.f,0.f}, 0, 0, 0);

            const float cxa[4] = {c01a.x, c01a.z, c23a.x, c23a.z};
            const float cya[4] = {c01a.y, c01a.w, c23a.y, c23a.w};
            const float cxb[4] = {c01b.x, c01b.z, c23b.x, c23b.z};
            const float cyb[4] = {c01b.y, c01b.w, c23b.y, c23b.w};

            float sv0[4], sv1[4];
            float pmax = -INFINITY;
            #pragma unroll
            for (int j = 0; j < 4; ++j) {
                const float dx = cq.x - cxa[j], dy = cq.y - cya[j];
                const float r  = fast_sqrt(fmaf(dx, dx, dy * dy));
                sv0[j] = fmaf(r, nb2, s0[j]);
                pmax = fmaxf(pmax, sv0[j]);
            }
            #pragma unroll
            for (int j = 0; j < 4; ++j) {
                const float dx = cq.x - cxb[j], dy = cq.y - cyb[j];
                const float r  = fast_sqrt(fmaf(dx, dx, dy * dy));
                sv1[j] = fmaf(r, nb2, s1[j]);
                pmax = fmaxf(pmax, sv1[j]);
            }
            pmax = fmaxf(pmax, __shfl_xor(pmax, 16));
            pmax = fmaxf(pmax, __shfl_xor(pmax, 32));

            if (__any(pmax > m)) {
                const float mn = fmaxf(m, pmax);
                const float f  = fast_exp2(m - mn);
                m = mn; l *= f; l2 *= f;
                #pragma unroll
                for (int j = 0; j < 4; ++j) {
                    const float fj = __shfl(f, 4 * g + j);
                    acc0[j] *= fj; acc1[j] *= fj;
                }
            }

            h4 pa0, pa1;
            #pragma unroll
            for (int j = 0; j < 4; ++j) {
                const float p = fast_exp2(sv0[j] - m);
                l += p; pa0[j] = (_Float16)p;
            }
            #pragma unroll
            for (int j = 0; j < 4; ++j) {
                const float p = fast_exp2(sv1[j] - m);
                l2 += p; pa1[j] = (_Float16)p;
            }
            acc0 = __builtin_amdgcn_mfma_f32_16x16x16f16(pa0, va0, acc0, 0, 0, 0);
            acc0 = __builtin_amdgcn_mfma_f32_16x16x16f16(pa1, va1, acc0, 0, 0, 0);
            acc1 = __builtin_amdgcn_mfma_f32_16x16x16f16(pa0, vb0, acc1, 0, 0, 0);
            acc1 = __builtin_amdgcn_mfma_f32_16x16x16f16(pa1, vb1, acc1, 0, 0, 0);
        }
    }

    // ---- tail: keys 1472..1499 (first 16 full, second group masked >=1500) ----
    {
        const int kb = KMAIN;
        const h8 kf0t = *(const h8*)(krow + (size_t)(kb + qc) * DH_ + 8 * g);
        const h8 kf1t = *(const h8*)(krow + (size_t)imin(kb + 16 + qc, N_ - 1) * DH_ + 8 * g);
        const h4 va0t = *(const h4*)(vrow0 + kb + 4 * g);
        const h4 vb0t = *(const h4*)(vrow1 + kb + 4 * g);
        const int t1 = imin(kb + 16 + 4 * g, N_ - 4);
        const h4 va1t = *(const h4*)(vrow0 + t1);
        const h4 vb1t = *(const h4*)(vrow1 + t1);

        const f4 s0 = __builtin_amdgcn_mfma_f32_16x16x32_f16(kf0t, qf, (f4){0.f,0.f,0.f,0.f}, 0, 0, 0);
        const f4 s1 = __builtin_amdgcn_mfma_f32_16x16x32_f16(kf1t, qf, (f4){0.f,0.f,0.f,0.f}, 0, 0, 0);

        float sv0[4], sv1[4];
        float pmax = -INFINITY;
        #pragma unroll
        for (int j = 0; j < 4; ++j) {
            const int k = kb + 4 * g + j;                    // <= 1487, valid
            const float2 ck = cpb[k];
            const float dx = cq.x - ck.x, dy = cq.y - ck.y;
            const float r  = fast_sqrt(fmaf(dx, dx, dy * dy));
            sv0[j] = fmaf(r, nb2, s0[j]);
            pmax = fmaxf(pmax, sv0[j]);
        }
        #pragma unroll
        for (int j = 0; j < 4; ++j) {
            const int k = kb + 16 + 4 * g + j;
            const float2 ck = cpb[imin(k, N_ - 1)];
            const float dx = cq.x - ck.x, dy = cq.y - ck.y;
            const float r  = fast_sqrt(fmaf(dx, dx, dy * dy));
            const float sc = fmaf(r, nb2, s1[j]);
            sv1[j] = (k < N_) ? sc : -1.0e30f;
            pmax = fmaxf(pmax, sv1[j]);
        }
        pmax = fmaxf(pmax, __shfl_xor(pmax, 16));
        pmax = fmaxf(pmax, __shfl_xor(pmax, 32));

        if (__any(pmax > m)) {
            const float mn = fmaxf(m, pmax);
            const float f  = fast_exp2(m - mn);
            m = mn; l *= f; l2 *= f;
            #pragma unroll
            for (int j = 0; j < 4; ++j) {
                const float fj = __shfl(f, 4 * g + j);
                acc0[j] *= fj; acc1[j] *= fj;
            }
        }

        h4 pa0, pa1;
        #pragma unroll
        for (int j = 0; j < 4; ++j) {
            const float p = fast_exp2(sv0[j] - m);
            l += p; pa0[j] = (_Float16)p;
        }
        #pragma unroll
        for (int j = 0; j < 4; ++j) {
            const float p = fast_exp2(sv1[j] - m);
            l2 += p; pa1[j] = (_Float16)p;
        }
        acc0 = __builtin_amdgcn_mfma_f32_16x16x16f16(pa0, va0t, acc0, 0, 0, 0);
        acc0 = __builtin_amdgcn_mfma_f32_16x16x16f16(pa1, va1t, acc0, 0, 0, 0);
        acc1 = __builtin_amdgcn_mfma_f32_16x16x16f16(pa0, vb0t, acc1, 0, 0, 0);
        acc1 = __builtin_amdgcn_mfma_f32_16x16x16f16(pa1, vb1t, acc1, 0, 0, 0);
    }

    l += l2;
    l += __shfl_xor(l, 16);
    l += __shfl_xor(l, 32);

    #pragma unroll
    for (int j = 0; j < 4; ++j) {
        const int qo = q0 + 4 * g + j;
        const float lj = __shfl(l, 4 * g + j);
        if (qo < N_) {
            const float inv = 1.0f / lj;
            float* dst = attnO + ((size_t)b * N_ + qo) * E_ + h * DH_;
            dst[qc]      = acc0[j] * inv;
            dst[16 + qc] = acc1[j] * inv;
        }
    }
}

// ============================ launcher ============================
extern "C" void kernel_launch(void* const* d_in, const int* in_sizes, int n_in,
                              void* d_out, int out_size, void* d_ws, size_t ws_size,
                              hipStream_t stream)
{
    (void)in_sizes; (void)n_in; (void)out_size; (void)ws_size;
    const float* feat   = (const float*)d_in[0];
    const float* points = (const float*)d_in[1];
    const float* ln1_w  = (const float*)d_in[2];
    const float* ln1_b  = (const float*)d_in[3];
    const float* beta_w = (const float*)d_in[4];
    const float* beta_b = (const float*)d_in[5];
    const float* in_w   = (const float*)d_in[6];
    const float* in_b   = (const float*)d_in[7];
    const float* out_w  = (const float*)d_in[8];
    const float* out_b  = (const float*)d_in[9];
    const float* ln2_w  = (const float*)d_in[10];
    const float* ln2_b  = (const float*)d_in[11];
    const float* fc1_w  = (const float*)d_in[12];
    const float* fc1_b  = (const float*)d_in[13];
    const float* fc2_w  = (const float*)d_in[14];
    const float* fc2_b  = (const float*)d_in[15];
    float* out = (float*)d_out;

    // workspace layout (float offsets); peak 6,984,000 floats = 27.9 MB
    float* ws   = (float*)d_ws;
    float*     x    = ws;                               // 1,536,000 f32
    float*     beta = x + 1536000;                      //    48,000 f32
    float2*    cpk  = (float2*)(beta + 48000);          //     6,000 float2
    _Float16*  qh   = (_Float16*)(beta + 48000 + 24000);// 1,536,000 f16
    _Float16*  kh   = qh + 1536000;
    _Float16*  vt   = kh + 1536000;
    float*     attn = (float*)(vt + 1536000);           // 1,536,000 f32
    float*     f2   = attn + 1536000;                   // 1,536,000 f32
    float*     y2   = x;                                // reuse (x dead after QKV)
    float*     h1   = (float*)qh;                       // reuse 3,072,000 f32

    ln_kernel<true><<<ROWS, 256, 0, stream>>>(feat, ln1_w, ln1_b, beta_w, beta_b,
                                              x, beta, points, cpk);

    dim3 gqkv((ROWS + 63) / 64, (3 * E_ + 63) / 64);
    gemm_bt<EPI_QKV><<<gqkv, 256, 0, stream>>>(x, in_w, in_b, nullptr, nullptr,
                                               ROWS, 3 * E_, E_, qh, kh, vt);

    attn_mfma<<<768, 256, 0, stream>>>(qh, kh, vt, cpk, beta, attn);

    dim3 gout((ROWS + 63) / 64, (E_ + 63) / 64);
    gemm_bt<EPI_BIAS_RES><<<gout, 256, 0, stream>>>(attn, out_w, out_b, feat, f2,
                                                    ROWS, E_, E_, nullptr, nullptr, nullptr);

    ln_kernel<false><<<ROWS, 256, 0, stream>>>(f2, ln2_w, ln2_b, nullptr, nullptr,
                                               y2, nullptr, nullptr, nullptr);

    dim3 gfc1((ROWS + 63) / 64, (HID_ + 63) / 64);
    gemm_bt<EPI_GELU><<<gfc1, 256, 0, stream>>>(y2, fc1_w, fc1_b, nullptr, h1,
                                                ROWS, HID_, E_, nullptr, nullptr, nullptr);

    dim3 gfc2((ROWS + 63) / 64, (E_ + 63) / 64);
    gemm_bt<EPI_BIAS><<<gfc2, 256, 0, stream>>>(h1, fc2_w, fc2_b, nullptr, out,
                                                ROWS, E_, HID_, nullptr, nullptr, nullptr);
}

// Round 13
// 232.985 us; speedup vs baseline: 1.3869x; 1.2664x over previous
//
#include <hip/hip_runtime.h>
#include <math.h>

// Problem constants (SelfAttentionBlock): B=4, N=1500, E=256, H=8, DH=32, HID=512
#define B_    4
#define N_    1500
#define E_    256
#define H_    8
#define DH_   32
#define HID_  512
#define ROWS  (B_ * N_)          // 6000
#define EPS_  1e-6f
#define SCALE_ 0.17677669529663687f   // 1/sqrt(DH)
#define LOG2E_ 1.4426950408889634f
#define QSC_   (SCALE_ * LOG2E_)      // folded into stored Q
#define KMAIN  1472                   // 23 * 64; tail = keys 1472..1499

typedef _Float16 h4 __attribute__((ext_vector_type(4)));
typedef _Float16 h8 __attribute__((ext_vector_type(8)));
typedef float    f4 __attribute__((ext_vector_type(4)));

__device__ __forceinline__ int imin(int a, int b) { return a < b ? a : b; }

__device__ __forceinline__ float fast_exp2(float x) {
#if __has_builtin(__builtin_amdgcn_exp2f)
    return __builtin_amdgcn_exp2f(x);
#else
    return exp2f(x);
#endif
}
__device__ __forceinline__ float fast_sqrt(float x) {
#if __has_builtin(__builtin_amdgcn_sqrtf)
    return __builtin_amdgcn_sqrtf(x);
#else
    return sqrtf(x);
#endif
}

// ============================ LayerNorm (+beta, +packed coords) ============================
// OUT16: write normalized output as f16 (feeds MFMA GEMMs); else f32.
template<bool WITH_BETA, bool OUT16>
__global__ __launch_bounds__(256)
void ln_kernel(const float* __restrict__ in, const float* __restrict__ w,
               const float* __restrict__ bvec, const float* __restrict__ beta_w,
               const float* __restrict__ beta_b, void* __restrict__ outp,
               float* __restrict__ betaO, const float* __restrict__ points,
               float2* __restrict__ cpk)
{
    const int row = blockIdx.x;          // b*N + n
    const int t   = threadIdx.x;         // 0..255
    __shared__ float sm[4], sv[4];

    float v = in[(size_t)row * E_ + t];

    float s = v;
    #pragma unroll
    for (int o = 32; o; o >>= 1) s += __shfl_xor(s, o);
    if ((t & 63) == 0) sm[t >> 6] = s;
    __syncthreads();
    const float mu = (sm[0] + sm[1] + sm[2] + sm[3]) * (1.0f / E_);

    const float d = v - mu;
    float s2 = d * d;
    #pragma unroll
    for (int o = 32; o; o >>= 1) s2 += __shfl_xor(s2, o);
    if ((t & 63) == 0) sv[t >> 6] = s2;
    __syncthreads();
    const float var = (sv[0] + sv[1] + sv[2] + sv[3]) * (1.0f / E_);

    const float xv = d * rsqrtf(var + EPS_) * w[t] + bvec[t];
    if (OUT16) ((_Float16*)outp)[(size_t)row * E_ + t] = (_Float16)xv;
    else       ((float*)outp)[(size_t)row * E_ + t] = xv;

    if (WITH_BETA) {
        if (t == 8) {   // pack xy coords once per row (aligned float2 table for attn)
            cpk[row] = make_float2(points[(size_t)row * 3 + 0], points[(size_t)row * 3 + 1]);
        }
        __shared__ float bs[H_][4];
        #pragma unroll
        for (int h = 0; h < H_; ++h) {
            float p = xv * beta_w[h * E_ + t];
            #pragma unroll
            for (int o = 32; o; o >>= 1) p += __shfl_xor(p, o);
            if ((t & 63) == 0) bs[h][t >> 6] = p;
        }
        __syncthreads();
        if (t < H_) {
            const int b = row / N_, n = row % N_;
            // fold log2e here: attention works natively in the exp2 domain
            betaO[((size_t)b * H_ + t) * N_ + n] =
                (bs[t][0] + bs[t][1] + bs[t][2] + bs[t][3] + beta_b[t]) * LOG2E_;
        }
    }
}

// ============================ fp32 GEMM (QKV only) ============================
__global__ __launch_bounds__(256)
void gemm_qkv(const float* __restrict__ A, const float* __restrict__ Bw,
              const float* __restrict__ bias, int M, int K,
              _Float16* __restrict__ qh, _Float16* __restrict__ kh,
              _Float16* __restrict__ vt)
{
    __shared__ float As[16][68];
    __shared__ float Bs[16][68];

    const int m0 = blockIdx.x * 64, n0 = blockIdx.y * 64;
    const int tid = threadIdx.x;
    const int tx = tid & 15, ty = tid >> 4;
    const int lr = tid >> 2;
    const int lk = (tid & 3) << 2;

    const bool mval = (m0 + lr) < M;
    const float* aptr = A  + (size_t)(m0 + lr) * K + lk;
    const float* bptr = Bw + (size_t)(n0 + lr) * K + lk;

    float acc[4][4] = {};

    for (int k0 = 0; k0 < K; k0 += 16) {
        float4 av = make_float4(0.f, 0.f, 0.f, 0.f);
        float4 bv = *(const float4*)(bptr + k0);      // n always < 768 (valid)
        if (mval) av = *(const float4*)(aptr + k0);
        As[lk + 0][lr] = av.x; As[lk + 1][lr] = av.y;
        As[lk + 2][lr] = av.z; As[lk + 3][lr] = av.w;
        Bs[lk + 0][lr] = bv.x; Bs[lk + 1][lr] = bv.y;
        Bs[lk + 2][lr] = bv.z; Bs[lk + 3][lr] = bv.w;
        __syncthreads();
        #pragma unroll
        for (int k = 0; k < 16; ++k) {
            float a[4], b[4];
            #pragma unroll
            for (int i = 0; i < 4; ++i) a[i] = As[k][ty * 4 + i];
            #pragma unroll
            for (int j = 0; j < 4; ++j) b[j] = Bs[k][tx * 4 + j];
            #pragma unroll
            for (int i = 0; i < 4; ++i)
                #pragma unroll
                for (int j = 0; j < 4; ++j)
                    acc[i][j] += a[i] * b[j];
        }
        __syncthreads();
    }

    // epilogue: pack f16 q/k (Q scaled by QSC_) and transposed V
    const int which = n0 >> 8;               // 0:q 1:k 2:v
    const int cb    = (n0 & 255) + tx * 4;   // 0..255, quad-aligned
    const int hh    = cb >> 5, dd = cb & 31;
    if (which < 2) {
        _Float16* base = (which == 0) ? qh : kh;
        const float scl = (which == 0) ? QSC_ : 1.0f;
        #pragma unroll
        for (int i = 0; i < 4; ++i) {
            const int mIdx = m0 + ty * 4 + i;
            if (mIdx >= M) continue;
            const int b = mIdx / N_, n = mIdx % N_;
            h4 pk;
            #pragma unroll
            for (int j = 0; j < 4; ++j)
                pk[j] = (_Float16)((acc[i][j] + bias[n0 + tx * 4 + j]) * scl);
            *(h4*)(base + (((size_t)b * H_ + hh) * N_ + n) * DH_ + dd) = pk;
        }
    } else {
        const int mq = m0 + ty * 4;
        if (mq < M) {
            const int b = mq / N_, n = mq % N_;
            #pragma unroll
            for (int j = 0; j < 4; ++j) {
                h4 pv;
                #pragma unroll
                for (int i = 0; i < 4; ++i)
                    pv[i] = (_Float16)(acc[i][j] + bias[n0 + tx * 4 + j]);
                *(h4*)(vt + (((size_t)b * H_ + hh) * DH_ + dd + j) * N_ + n) = pv;
            }
        }
    }
}

// ============================ f16 MFMA GEMM (OUT / FC1 / FC2) ============================
// C[M,Nn] = A_h[M,K] * f16(W[Nn,K])^T + bias (+res / GELU). 64x64 tile, BK=32,
// 4 waves; wave w owns n-cols 16w..16w+15; mfma(Wfrag, Afrag): lane(qc,g) acc[mi][j]
// = C[m0+16mi+qc][n0+16w+4g+j] -> 4-consecutive-n epilogue stores.
// LDS rows padded to 40 h16 (80B): b128 frag reads 2-way-bank = free (m136).
enum { MEPI_RES = 0, MEPI_GELU = 1, MEPI_BIAS = 2 };

template<int EPI>
__global__ __launch_bounds__(256)
void gemm_mfma(const _Float16* __restrict__ A, const float* __restrict__ W,
               const float* __restrict__ bias, const float* __restrict__ res,
               float* __restrict__ Cf, _Float16* __restrict__ Ch,
               int M, int Nn, int K)
{
    __shared__ _Float16 As[64][40];
    __shared__ _Float16 Ws[64][40];

    const int m0 = blockIdx.x * 64, n0 = blockIdx.y * 64;
    const int tid  = threadIdx.x;
    const int wid  = tid >> 6;
    const int lane = tid & 63;
    const int qc = lane & 15, g = lane >> 4;
    const int srow = tid >> 2;             // 0..63
    const int skq  = (tid & 3) * 8;        // 0,8,16,24

    const bool mval = (m0 + srow) < M;
    const _Float16* ap = A + (size_t)(m0 + srow) * K + skq;
    const float*    wp = W + (size_t)(n0 + srow) * K + skq;  // n rows always valid (Nn%64==0)

    f4 acc[4] = {{0.f,0.f,0.f,0.f},{0.f,0.f,0.f,0.f},{0.f,0.f,0.f,0.f},{0.f,0.f,0.f,0.f}};

    for (int k0 = 0; k0 < K; k0 += 32) {
        __syncthreads();
        h8 av = {};
        if (mval) av = *(const h8*)(ap + k0);
        *(h8*)&As[srow][skq] = av;
        const float4 w0 = *(const float4*)(wp + k0);
        const float4 w1 = *(const float4*)(wp + k0 + 4);
        h8 wv;
        wv[0] = (_Float16)w0.x; wv[1] = (_Float16)w0.y;
        wv[2] = (_Float16)w0.z; wv[3] = (_Float16)w0.w;
        wv[4] = (_Float16)w1.x; wv[5] = (_Float16)w1.y;
        wv[6] = (_Float16)w1.z; wv[7] = (_Float16)w1.w;
        *(h8*)&Ws[srow][skq] = wv;
        __syncthreads();

        const h8 aop = *(const h8*)&Ws[16 * wid + qc][8 * g];
        #pragma unroll
        for (int mi = 0; mi < 4; ++mi) {
            const h8 bop = *(const h8*)&As[16 * mi + qc][8 * g];
            acc[mi] = __builtin_amdgcn_mfma_f32_16x16x32_f16(aop, bop, acc[mi], 0, 0, 0);
        }
    }

    const int nb = n0 + 16 * wid + 4 * g;
    #pragma unroll
    for (int mi = 0; mi < 4; ++mi) {
        const int m = m0 + 16 * mi + qc;
        if (m >= M) continue;
        const float v0 = acc[mi][0] + bias[nb + 0];
        const float v1 = acc[mi][1] + bias[nb + 1];
        const float v2 = acc[mi][2] + bias[nb + 2];
        const float v3 = acc[mi][3] + bias[nb + 3];
        if (EPI == MEPI_RES) {
            const float4 rf = *(const float4*)(res + (size_t)m * Nn + nb);
            *(float4*)(Cf + (size_t)m * Nn + nb) =
                make_float4(v0 + rf.x, v1 + rf.y, v2 + rf.z, v3 + rf.w);
        } else if (EPI == MEPI_GELU) {
            h4 o;
            o[0] = (_Float16)(v0 * 0.5f * (1.0f + erff(v0 * 0.70710678118654752f)));
            o[1] = (_Float16)(v1 * 0.5f * (1.0f + erff(v1 * 0.70710678118654752f)));
            o[2] = (_Float16)(v2 * 0.5f * (1.0f + erff(v2 * 0.70710678118654752f)));
            o[3] = (_Float16)(v3 * 0.5f * (1.0f + erff(v3 * 0.70710678118654752f)));
            *(h4*)(Ch + (size_t)m * Nn + nb) = o;
        } else {
            *(float4*)(Cf + (size_t)m * Nn + nb) = make_float4(v0, v1, v2, v3);
        }
    }
}

// ============================ MFMA flash attention (LDS V + XCD swizzle) ============
// Unchanged from r11 except output is f16 (feeds the MFMA out-projection).
__global__ __launch_bounds__(256)
void attn_mfma(const _Float16* __restrict__ qh, const _Float16* __restrict__ kh,
               const _Float16* __restrict__ vt, const float2* __restrict__ cpk,
               const float* __restrict__ betaB, _Float16* __restrict__ attnO)
{
    // bijective swizzle (768 = 96 x 8): dispatch i -> XCD i%8 (round-robin heuristic)
    const int i    = blockIdx.x;            // 0..767
    const int slot = i >> 3;                // 0..95
    const int bh   = (i & 7) + 8 * (slot / 24);   // head on XCD bh%8
    const int qblk = slot % 24;

    const int b  = bh >> 3, h = bh & 7;
    const int tid  = threadIdx.x;
    const int wid  = tid >> 6;
    const int lane = tid & 63;
    const int qc = lane & 15;            // q col in S' / d col in O
    const int g  = lane >> 4;            // 16-lane group
    const int q0 = qblk * 64 + wid * 16;
    const int qcl = imin(q0 + qc, N_ - 1);

    __shared__ _Float16 Vs[32][72];      // V^T tile [d][key64], rows padded to 144B

    const h8 qf = *(const h8*)(qh + ((size_t)bh * N_ + qcl) * DH_ + 8 * g);
    const float2 cq  = cpk[b * N_ + qcl];
    const float  nb2 = -betaB[(size_t)bh * N_ + qcl];   // -(beta*log2e)

    const _Float16* krow  = kh + (size_t)bh * N_ * DH_;
    const _Float16* vtb   = vt + (size_t)bh * DH_ * N_;
    const _Float16* vrow0 = vtb + (size_t)qc * N_;        // tail path
    const _Float16* vrow1 = vtb + (size_t)(16 + qc) * N_; // tail path
    const float2*   cpb   = cpk + b * N_;

    const int r0 = tid >> 4;             // 0..15
    const int r1 = r0 + 16;              // 16..31
    const int c0 = (tid & 15) * 4;       // 0..60 (h16 units)

    float m = -INFINITY, l = 0.0f, l2 = 0.0f;
    f4 acc0 = {0.f, 0.f, 0.f, 0.f}, acc1 = {0.f, 0.f, 0.f, 0.f};

    for (int tkb = 0; tkb < KMAIN; tkb += 64) {
        __syncthreads();
        *(h4*)&Vs[r0][c0] = *(const h4*)(vtb + (size_t)r0 * N_ + tkb + c0);
        *(h4*)&Vs[r1][c0] = *(const h4*)(vtb + (size_t)r1 * N_ + tkb + c0);
        __syncthreads();

        #pragma unroll
        for (int s = 0; s < 2; ++s) {
            const int kb = tkb + 32 * s;
            const h8 kf0 = *(const h8*)(krow + (size_t)(kb + qc) * DH_ + 8 * g);
            const h8 kf1 = *(const h8*)(krow + (size_t)(kb + 16 + qc) * DH_ + 8 * g);
            const h4 va0 = *(const h4*)&Vs[qc][32 * s + 4 * g];
            const h4 va1 = *(const h4*)&Vs[qc][32 * s + 16 + 4 * g];
            const h4 vb0 = *(const h4*)&Vs[16 + qc][32 * s + 4 * g];
            const h4 vb1 = *(const h4*)&Vs[16 + qc][32 * s + 16 + 4 * g];
            const float4* cpt = (const float4*)(cpb + kb);
            const float4 c01a = cpt[2 * g],     c23a = cpt[2 * g + 1];
            const float4 c01b = cpt[8 + 2 * g], c23b = cpt[8 + 2 * g + 1];

            const f4 s0 = __builtin_amdgcn_mfma_f32_16x16x32_f16(kf0, qf, (f4){0.f,0.f,0.f,0.f}, 0, 0, 0);
            const f4 s1 = __builtin_amdgcn_mfma_f32_16x16x32_f16(kf1, qf, (f4){0.f,0.f,0.f,0.f}, 0, 0, 0);

            const float cxa[4] = {c01a.x, c01a.z, c23a.x, c23a.z};
            const float cya[4] = {c01a.y, c01a.w, c23a.y, c23a.w};
            const float cxb[4] = {c01b.x, c01b.z, c23b.x, c23b.z};
            const float cyb[4] = {c01b.y, c01b.w, c23b.y, c23b.w};

            float sv0[4], sv1[4];
            float pmax = -INFINITY;
            #pragma unroll
            for (int j = 0; j < 4; ++j) {
                const float dx = cq.x - cxa[j], dy = cq.y - cya[j];
                const float r  = fast_sqrt(fmaf(dx, dx, dy * dy));
                sv0[j] = fmaf(r, nb2, s0[j]);
                pmax = fmaxf(pmax, sv0[j]);
            }
            #pragma unroll
            for (int j = 0; j < 4; ++j) {
                const float dx = cq.x - cxb[j], dy = cq.y - cyb[j];
                const float r  = fast_sqrt(fmaf(dx, dx, dy * dy));
                sv1[j] = fmaf(r, nb2, s1[j]);
                pmax = fmaxf(pmax, sv1[j]);
            }
            pmax = fmaxf(pmax, __shfl_xor(pmax, 16));
            pmax = fmaxf(pmax, __shfl_xor(pmax, 32));

            if (__any(pmax > m)) {
                const float mn = fmaxf(m, pmax);
                const float f  = fast_exp2(m - mn);
                m = mn; l *= f; l2 *= f;
                #pragma unroll
                for (int j = 0; j < 4; ++j) {
                    const float fj = __shfl(f, 4 * g + j);
                    acc0[j] *= fj; acc1[j] *= fj;
                }
            }

            h4 pa0, pa1;
            #pragma unroll
            for (int j = 0; j < 4; ++j) {
                const float p = fast_exp2(sv0[j] - m);
                l += p; pa0[j] = (_Float16)p;
            }
            #pragma unroll
            for (int j = 0; j < 4; ++j) {
                const float p = fast_exp2(sv1[j] - m);
                l2 += p; pa1[j] = (_Float16)p;
            }
            acc0 = __builtin_amdgcn_mfma_f32_16x16x16f16(pa0, va0, acc0, 0, 0, 0);
            acc0 = __builtin_amdgcn_mfma_f32_16x16x16f16(pa1, va1, acc0, 0, 0, 0);
            acc1 = __builtin_amdgcn_mfma_f32_16x16x16f16(pa0, vb0, acc1, 0, 0, 0);
            acc1 = __builtin_amdgcn_mfma_f32_16x16x16f16(pa1, vb1, acc1, 0, 0, 0);
        }
    }

    // ---- tail: keys 1472..1499 ----
    {
        const int kb = KMAIN;
        const h8 kf0t = *(const h8*)(krow + (size_t)(kb + qc) * DH_ + 8 * g);
        const h8 kf1t = *(const h8*)(krow + (size_t)imin(kb + 16 + qc, N_ - 1) * DH_ + 8 * g);
        const h4 va0t = *(const h4*)(vrow0 + kb + 4 * g);
        const h4 vb0t = *(const h4*)(vrow1 + kb + 4 * g);
        const int t1 = imin(kb + 16 + 4 * g, N_ - 4);
        const h4 va1t = *(const h4*)(vrow0 + t1);
        const h4 vb1t = *(const h4*)(vrow1 + t1);

        const f4 s0 = __builtin_amdgcn_mfma_f32_16x16x32_f16(kf0t, qf, (f4){0.f,0.f,0.f,0.f}, 0, 0, 0);
        const f4 s1 = __builtin_amdgcn_mfma_f32_16x16x32_f16(kf1t, qf, (f4){0.f,0.f,0.f,0.f}, 0, 0, 0);

        float sv0[4], sv1[4];
        float pmax = -INFINITY;
        #pragma unroll
        for (int j = 0; j < 4; ++j) {
            const int k = kb + 4 * g + j;
            const float2 ck = cpb[k];
            const float dx = cq.x - ck.x, dy = cq.y - ck.y;
            const float r  = fast_sqrt(fmaf(dx, dx, dy * dy));
            sv0[j] = fmaf(r, nb2, s0[j]);
            pmax = fmaxf(pmax, sv0[j]);
        }
        #pragma unroll
        for (int j = 0; j < 4; ++j) {
            const int k = kb + 16 + 4 * g + j;
            const float2 ck = cpb[imin(k, N_ - 1)];
            const float dx = cq.x - ck.x, dy = cq.y - ck.y;
            const float r  = fast_sqrt(fmaf(dx, dx, dy * dy));
            const float sc = fmaf(r, nb2, s1[j]);
            sv1[j] = (k < N_) ? sc : -1.0e30f;
            pmax = fmaxf(pmax, sv1[j]);
        }
        pmax = fmaxf(pmax, __shfl_xor(pmax, 16));
        pmax = fmaxf(pmax, __shfl_xor(pmax, 32));

        if (__any(pmax > m)) {
            const float mn = fmaxf(m, pmax);
            const float f  = fast_exp2(m - mn);
            m = mn; l *= f; l2 *= f;
            #pragma unroll
            for (int j = 0; j < 4; ++j) {
                const float fj = __shfl(f, 4 * g + j);
                acc0[j] *= fj; acc1[j] *= fj;
            }
        }

        h4 pa0, pa1;
        #pragma unroll
        for (int j = 0; j < 4; ++j) {
            const float p = fast_exp2(sv0[j] - m);
            l += p; pa0[j] = (_Float16)p;
        }
        #pragma unroll
        for (int j = 0; j < 4; ++j) {
            const float p = fast_exp2(sv1[j] - m);
            l2 += p; pa1[j] = (_Float16)p;
        }
        acc0 = __builtin_amdgcn_mfma_f32_16x16x16f16(pa0, va0t, acc0, 0, 0, 0);
        acc0 = __builtin_amdgcn_mfma_f32_16x16x16f16(pa1, va1t, acc0, 0, 0, 0);
        acc1 = __builtin_amdgcn_mfma_f32_16x16x16f16(pa0, vb0t, acc1, 0, 0, 0);
        acc1 = __builtin_amdgcn_mfma_f32_16x16x16f16(pa1, vb1t, acc1, 0, 0, 0);
    }

    l += l2;
    l += __shfl_xor(l, 16);
    l += __shfl_xor(l, 32);

    #pragma unroll
    for (int j = 0; j < 4; ++j) {
        const int qo = q0 + 4 * g + j;
        const float lj = __shfl(l, 4 * g + j);
        if (qo < N_) {
            const float inv = 1.0f / lj;
            _Float16* dst = attnO + ((size_t)b * N_ + qo) * E_ + h * DH_;
            dst[qc]      = (_Float16)(acc0[j] * inv);
            dst[16 + qc] = (_Float16)(acc1[j] * inv);
        }
    }
}

// ============================ launcher ============================
extern "C" void kernel_launch(void* const* d_in, const int* in_sizes, int n_in,
                              void* d_out, int out_size, void* d_ws, size_t ws_size,
                              hipStream_t stream)
{
    (void)in_sizes; (void)n_in; (void)out_size; (void)ws_size;
    const float* feat   = (const float*)d_in[0];
    const float* points = (const float*)d_in[1];
    const float* ln1_w  = (const float*)d_in[2];
    const float* ln1_b  = (const float*)d_in[3];
    const float* beta_w = (const float*)d_in[4];
    const float* beta_b = (const float*)d_in[5];
    const float* in_w   = (const float*)d_in[6];
    const float* in_b   = (const float*)d_in[7];
    const float* out_w  = (const float*)d_in[8];
    const float* out_b  = (const float*)d_in[9];
    const float* ln2_w  = (const float*)d_in[10];
    const float* ln2_b  = (const float*)d_in[11];
    const float* fc1_w  = (const float*)d_in[12];
    const float* fc1_b  = (const float*)d_in[13];
    const float* fc2_w  = (const float*)d_in[14];
    const float* fc2_b  = (const float*)d_in[15];
    float* out = (float*)d_out;

    // workspace layout (float offsets); peak 6,216,000 floats = 24.9 MB
    float* ws   = (float*)d_ws;
    float*     x      = ws;                               // 1,536,000 f32 (LN1 out, QKV A)
    float*     beta   = x + 1536000;                      //    48,000 f32
    float2*    cpk    = (float2*)(beta + 48000);          //     6,000 float2
    _Float16*  qh     = (_Float16*)(beta + 48000 + 24000);// 1,536,000 f16
    _Float16*  kh     = qh + 1536000;
    _Float16*  vt     = kh + 1536000;
    _Float16*  attn_h = vt + 1536000;                     // 1,536,000 f16 (attn out)
    float*     f2     = (float*)(attn_h + 1536000);       // 1,536,000 f32 (residual)
    _Float16*  y2h    = (_Float16*)x;                     // reuse (x dead after QKV)
    _Float16*  h1h    = qh;                               // reuse 3,072,000 f16 (qh+kh dead)

    ln_kernel<true, false><<<ROWS, 256, 0, stream>>>(feat, ln1_w, ln1_b, beta_w, beta_b,
                                                     x, beta, points, cpk);

    dim3 gqkv((ROWS + 63) / 64, (3 * E_) / 64);
    gemm_qkv<<<gqkv, 256, 0, stream>>>(x, in_w, in_b, ROWS, E_, qh, kh, vt);

    attn_mfma<<<768, 256, 0, stream>>>(qh, kh, vt, cpk, beta, attn_h);

    dim3 gout((ROWS + 63) / 64, E_ / 64);
    gemm_mfma<MEPI_RES><<<gout, 256, 0, stream>>>(attn_h, out_w, out_b, feat,
                                                  f2, nullptr, ROWS, E_, E_);

    ln_kernel<false, true><<<ROWS, 256, 0, stream>>>(f2, ln2_w, ln2_b, nullptr, nullptr,
                                                     y2h, nullptr, nullptr, nullptr);

    dim3 gfc1((ROWS + 63) / 64, HID_ / 64);
    gemm_mfma<MEPI_GELU><<<gfc1, 256, 0, stream>>>(y2h, fc1_w, fc1_b, nullptr,
                                                   nullptr, h1h, ROWS, HID_, E_);

    dim3 gfc2((ROWS + 63) / 64, E_ / 64);
    gemm_mfma<MEPI_BIAS><<<gfc2, 256, 0, stream>>>(h1h, fc2_w, fc2_b, nullptr,
                                                   out, nullptr, ROWS, E_, HID_);
}